// Round 8
// baseline (809.269 us; speedup 1.0000x reference)
//
#include <hip/hip_runtime.h>
#include <hip/hip_fp16.h>

#define N_NODES 100000
#define N_EDGES 1000000
#define C 128
#define NL 3
#define G 64
#define EPS 1e-5f
#define SLOPE 0.01f

#define SCAN_CH 392
#define SCAN_BLOCKS 256   // ceil(100000/392) == 256 exactly

// fp16 unpack: 4 channels per lane = 8 bytes (uint2)
static __device__ __forceinline__ float4 unpack_half4(uint2 u) {
  __half2 lo = *reinterpret_cast<__half2*>(&u.x);
  __half2 hi = *reinterpret_cast<__half2*>(&u.y);
  float2 a = __half22float2(lo);
  float2 b = __half22float2(hi);
  return make_float4(a.x, a.y, b.x, b.y);
}
static __device__ __forceinline__ uint2 pack_half4(float4 f) {
  __half2 lo = __floats2half2_rn(f.x, f.y);
  __half2 hi = __floats2half2_rn(f.z, f.w);
  uint2 u;
  u.x = *reinterpret_cast<unsigned int*>(&lo);
  u.y = *reinterpret_cast<unsigned int*>(&hi);
  return u;
}

// ---------------- preprocessing ----------------

__global__ __launch_bounds__(256) void hist_edges_k(const int* __restrict__ dst, int* __restrict__ cnt) {
  int i = blockIdx.x * 256 + threadIdx.x;
  if (i < N_EDGES) atomicAdd(&cnt[dst[i]], 1);
}

// batch is sorted: per-graph counts via binary search, no atomics. 64 threads.
__global__ __launch_bounds__(64) void graph_cnt_k(const int* __restrict__ batch, float* __restrict__ cntinv) {
  const int g = threadIdx.x;
  if (g >= G) return;
  auto lb = [&](int key) {
    int lo = 0, hi = N_NODES;
    while (lo < hi) { int mid = (lo + hi) >> 1; if (batch[mid] < key) lo = mid + 1; else hi = mid; }
    return lo;
  };
  const int a = lb(g), b = lb(g + 1);
  cntinv[g] = 1.0f / fmaxf((float)(b - a), 1.0f);
}

// multi-block scan, phase 1: per-chunk sums (coalesced)
__global__ __launch_bounds__(256) void scan1_k(const int* __restrict__ cnt, int* __restrict__ bsum) {
  __shared__ int red[256];
  const int b = blockIdx.x, t = threadIdx.x;
  const int s = b * SCAN_CH;
  const int e = min(s + SCAN_CH, N_NODES);
  int sum = 0;
  for (int i = s + t; i < e; i += 256) sum += cnt[i];
  red[t] = sum;
  __syncthreads();
  for (int off = 128; off > 0; off >>= 1) {
    if (t < off) red[t] += red[t + off];
    __syncthreads();
  }
  if (t == 0) bsum[b] = red[0];
}

// phase 2: exclusive scan of 256 block sums (one block)
__global__ __launch_bounds__(256) void scan2_k(const int* __restrict__ bsum, int* __restrict__ boff,
                                               int* __restrict__ row_ptr) {
  __shared__ int sh[256];
  const int t = threadIdx.x;
  sh[t] = bsum[t];
  __syncthreads();
  for (int off = 1; off < 256; off <<= 1) {
    int v = sh[t];
    int add = (t >= off) ? sh[t - off] : 0;
    __syncthreads();
    sh[t] = v + add;
    __syncthreads();
  }
  boff[t] = t ? sh[t - 1] : 0;
  if (t == 255) row_ptr[N_NODES] = sh[255];
}

// phase 3: per-chunk exclusive scan + global offset -> row_ptr, cursor
__global__ __launch_bounds__(256) void scan3_k(const int* __restrict__ cnt, const int* __restrict__ boff,
                                               int* __restrict__ row_ptr, int* __restrict__ cursor) {
  __shared__ int vals[SCAN_CH];
  __shared__ int tsum[256];
  const int b = blockIdx.x, t = threadIdx.x;
  const int s = b * SCAN_CH;
  const int e = min(s + SCAN_CH, N_NODES);
  const int len = e - s;
  for (int i = t; i < len; i += 256) vals[i] = cnt[s + i];
  __syncthreads();
  const int i0 = 2 * t, i1 = 2 * t + 1;
  const int a = (i0 < len) ? vals[i0] : 0;
  const int bb = (i1 < len) ? vals[i1] : 0;
  tsum[t] = a + bb;
  __syncthreads();
  for (int off = 1; off < 256; off <<= 1) {
    int v = tsum[t];
    int add = (t >= off) ? tsum[t - off] : 0;
    __syncthreads();
    tsum[t] = v + add;
    __syncthreads();
  }
  const int pre = (t ? tsum[t - 1] : 0) + boff[b];
  if (i0 < len) { row_ptr[s + i0] = pre; cursor[s + i0] = pre; }
  if (i1 < len) { row_ptr[s + i1] = pre + a; cursor[s + i1] = pre + a; }
}

__global__ __launch_bounds__(256) void dinv_k(const int* __restrict__ cnt, float* __restrict__ dinv) {
  int i = blockIdx.x * 256 + threadIdx.x;
  if (i < N_NODES) dinv[i] = rsqrtf((float)cnt[i] + 1.0f);   // deg + self-loop
}

__global__ __launch_bounds__(256) void scatter_k(const int* __restrict__ src, const int* __restrict__ dst,
                                                 int* __restrict__ cursor, int* __restrict__ src_s) {
  int i = blockIdx.x * 256 + threadIdx.x;
  if (i < N_EDGES) {
    int d = dst[i];
    int p = atomicAdd(&cursor[d], 1);
    src_s[p] = src[i];
  }
}

// ---------------- per-layer kernels ----------------

// Yh[n] = fp16( dinv[n] * (X[n] @ W) )   fp32 math, fp16 store via LDS repack
// (pack is quarantined in a post-sync region where the accumulator is dead -> no spill; verified R6)
__global__ __launch_bounds__(256) void gemm_y_k(const float* __restrict__ X, const float* __restrict__ W,
                                                const float* __restrict__ dinv, __half* __restrict__ Yh) {
  __shared__ float xs[32 * C];   // 16 KB
  __shared__ float ws[32 * C];   // 16 KB (k-tile)
  const int tid = threadIdx.x;
  const int cg = tid & 31;    // cols cg*4 .. cg*4+3
  const int rs = tid >> 5;    // rows rs, rs+8, rs+16, rs+24
  const int row0 = blockIdx.x * 32;
  {
    const float4* X4 = (const float4*)(X + (size_t)row0 * C);
    float4* s4 = (float4*)xs;
#pragma unroll
    for (int i = 0; i < 4; i++) s4[tid + i * 256] = X4[tid + i * 256];
  }
  float4 acc[4];
#pragma unroll
  for (int r = 0; r < 4; r++) acc[r] = make_float4(0.f, 0.f, 0.f, 0.f);
  const float4* xs4 = (const float4*)xs;
  const float4* ws4 = (const float4*)ws;
#pragma unroll
  for (int kt = 0; kt < 4; kt++) {
    __syncthreads();
    {
      const float4* W4 = (const float4*)(W + (size_t)kt * 32 * C);
      float4* s4 = (float4*)ws;
#pragma unroll
      for (int i = 0; i < 4; i++) s4[tid + i * 256] = W4[tid + i * 256];
    }
    __syncthreads();
#pragma unroll
    for (int k4 = 0; k4 < 8; k4++) {
      float4 xv[4];
#pragma unroll
      for (int r = 0; r < 4; r++) xv[r] = xs4[(rs + 8 * r) * 32 + kt * 8 + k4];
#pragma unroll
      for (int j = 0; j < 4; j++) {
        float4 wv = ws4[(k4 * 4 + j) * 32 + cg];
#pragma unroll
        for (int r = 0; r < 4; r++) {
          float xsc = (j == 0) ? xv[r].x : (j == 1) ? xv[r].y : (j == 2) ? xv[r].z : xv[r].w;
          acc[r].x += xsc * wv.x;
          acc[r].y += xsc * wv.y;
          acc[r].z += xsc * wv.z;
          acc[r].w += xsc * wv.w;
        }
      }
    }
  }
  // stage scaled outputs to LDS (xs is dead), then repack fp16 with minimal live state
  __syncthreads();
  {
    float4* st = (float4*)xs;
#pragma unroll
    for (int r = 0; r < 4; r++) {
      const int row = row0 + rs + 8 * r;
      const float dn = dinv[row];
      float4 o = acc[r];
      o.x *= dn; o.y *= dn; o.z *= dn; o.w *= dn;
      st[(rs + 8 * r) * 32 + cg] = o;
    }
  }
  __syncthreads();
  {
    uint2* Yh2 = (uint2*)Yh;
#pragma unroll
    for (int i = 0; i < 4; i++) {
      const int idx = tid + i * 256;
      Yh2[(size_t)row0 * 32 + idx] = pack_half4(((const float4*)xs)[idx]);
    }
  }
}

__device__ __forceinline__ void flush4(float* dst, int g, int lane, float4 a) {
  float* p = dst + g * C + lane * 4;
  atomicAdd(p + 0, a.x);
  atomicAdd(p + 1, a.y);
  atomicAdd(p + 2, a.z);
  atomicAdd(p + 3, a.w);
}

// out[n] = dinv[n]*(Yh[n] + sum_{e in CSR[n]} Yh[src_e]) + b    (32 lanes per node)
// + fused GraphNorm stats via BLOCK-BATCHED atomics: 8 subgroups stage o/o^2 in LDS,
// one tree-reduce, ONE 256-atomic flush per block (3.2M total, vs R6's fatal 25.6M
// per-node flushes; gn_sums' 1.6M batched atomics ran fine, this is the same pattern).
__global__ __launch_bounds__(256) void agg_k(const __half* __restrict__ Yh, const int* __restrict__ row_ptr,
                                             const int* __restrict__ src_s, const float* __restrict__ dinv,
                                             const float* __restrict__ bias, const int* __restrict__ batch,
                                             float* __restrict__ meansum, float* __restrict__ varsum,
                                             float* __restrict__ out) {
  __shared__ float ls[8 * C];   // 4 KB: per-subgroup o
  __shared__ float lq[8 * C];   // 4 KB: per-subgroup o^2
  __shared__ int gsh[8];
  const int sub = threadIdx.x >> 5;
  const int lane = threadIdx.x & 31;
  const int n = blockIdx.x * 8 + sub;   // grid is exact: 12500*8 = 100000
  const uint2* Y2 = (const uint2*)Yh;   // 4 halves (8 B) per lane, 32 lanes per row
  float4 acc = unpack_half4(Y2[(size_t)n * 32 + lane]);
  const int e0 = row_ptr[n];
  const int e1 = row_ptr[n + 1];
  for (int e = e0; e < e1; e += 8) {
    const int c = e1 - e;   // >= 1
    int idx[8];
#pragma unroll
    for (int i = 0; i < 8; i++) idx[i] = src_s[(e + i < e1) ? e + i : e1 - 1];
    uint2 v[8];
#pragma unroll
    for (int i = 0; i < 8; i++) v[i] = Y2[(size_t)idx[i] * 32 + lane];
#pragma unroll
    for (int i = 0; i < 8; i++) {
      const float4 f = unpack_half4(v[i]);
      const float m = (i < c) ? 1.f : 0.f;
      acc.x += f.x * m;
      acc.y += f.y * m;
      acc.z += f.z * m;
      acc.w += f.w * m;
    }
  }
  const float dn = dinv[n];
  const float4 bb = ((const float4*)bias)[lane];
  float4 o;
  o.x = acc.x * dn + bb.x;
  o.y = acc.y * dn + bb.y;
  o.z = acc.z * dn + bb.z;
  o.w = acc.w * dn + bb.w;
  ((float4*)out)[(size_t)n * 32 + lane] = o;

  // ---- stats ----
  const int g = batch[n];
  ((float4*)(ls + sub * C))[lane] = o;
  ((float4*)(lq + sub * C))[lane] = make_float4(o.x * o.x, o.y * o.y, o.z * o.z, o.w * o.w);
  if (lane == 0) gsh[sub] = g;
  __syncthreads();
  if (gsh[0] == gsh[7]) {          // batch sorted -> all 8 nodes in same graph (common case)
    const int t = threadIdx.x;
    const int ch = t & 127;
    const float* arr = (t < 128) ? ls : lq;
    float s = 0.f;
#pragma unroll
    for (int k = 0; k < 8; k++) s += arr[k * C + ch];
    float* dstp = (t < 128) ? meansum : varsum;
    atomicAdd(&dstp[gsh[0] * C + ch], s);
  } else {                          // graph boundary inside block (~63 blocks): per-node flush
    flush4(meansum, g, lane, o);
    flush4(varsum, g, lane, make_float4(o.x * o.x, o.y * o.y, o.z * o.z, o.w * o.w));
  }
}

// Fused: A <- leaky(graphnorm(A)) in place (history slot), then Yh = fp16(dinv * (A @ W)) for next layer.
__global__ __launch_bounds__(256) void apply_gemm_k(
    float* __restrict__ A, const int* __restrict__ batch,
    const float* __restrict__ meansum, const float* __restrict__ varsum,
    const float* __restrict__ cntinv,
    const float* __restrict__ gw, const float* __restrict__ gb, const float* __restrict__ gms,
    const float* __restrict__ W, const float* __restrict__ dinv, __half* __restrict__ Yh) {
  __shared__ float xs[32 * C];   // 16 KB
  __shared__ float ws[32 * C];   // 16 KB
  const int tid = threadIdx.x;
  const int cg = tid & 31;
  const int rs = tid >> 5;
  const int row0 = blockIdx.x * 32;
  const float4 wv4 = ((const float4*)gw)[cg];
  const float4 bv4 = ((const float4*)gb)[cg];
  const float4 sv4 = ((const float4*)gms)[cg];
  float4* A4 = (float4*)A;
  const float4* MS4 = (const float4*)meansum;
  const float4* VS4 = (const float4*)varsum;
  float4* xs4w = (float4*)xs;
#pragma unroll
  for (int r = 0; r < 4; r++) {
    const int row = row0 + rs + 8 * r;
    const int g = batch[row];
    const float ci = cntinv[g];
    const float4 ms = MS4[g * 32 + cg];
    const float4 vs = VS4[g * 32 + cg];
    float4 v = A4[(size_t)row * 32 + cg];
    float m, msc, var, rr;
    m = ms.x * ci; msc = m * sv4.x; var = vs.x * ci - msc * (2.f * m - msc);
    rr = rsqrtf(var + EPS); v.x = (v.x - msc) * rr * wv4.x + bv4.x; v.x = (v.x > 0.f) ? v.x : SLOPE * v.x;
    m = ms.y * ci; msc = m * sv4.y; var = vs.y * ci - msc * (2.f * m - msc);
    rr = rsqrtf(var + EPS); v.y = (v.y - msc) * rr * wv4.y + bv4.y; v.y = (v.y > 0.f) ? v.y : SLOPE * v.y;
    m = ms.z * ci; msc = m * sv4.z; var = vs.z * ci - msc * (2.f * m - msc);
    rr = rsqrtf(var + EPS); v.z = (v.z - msc) * rr * wv4.z + bv4.z; v.z = (v.z > 0.f) ? v.z : SLOPE * v.z;
    m = ms.w * ci; msc = m * sv4.w; var = vs.w * ci - msc * (2.f * m - msc);
    rr = rsqrtf(var + EPS); v.w = (v.w - msc) * rr * wv4.w + bv4.w; v.w = (v.w > 0.f) ? v.w : SLOPE * v.w;
    A4[(size_t)row * 32 + cg] = v;            // history slot (activated layer output)
    xs4w[(rs + 8 * r) * 32 + cg] = v;         // stage for GEMM, same layout as gemm_y_k
  }
  float4 acc[4];
#pragma unroll
  for (int r = 0; r < 4; r++) acc[r] = make_float4(0.f, 0.f, 0.f, 0.f);
  const float4* xs4 = (const float4*)xs;
  const float4* ws4 = (const float4*)ws;
#pragma unroll
  for (int kt = 0; kt < 4; kt++) {
    __syncthreads();
    {
      const float4* W4 = (const float4*)(W + (size_t)kt * 32 * C);
      float4* s4 = (float4*)ws;
#pragma unroll
      for (int i = 0; i < 4; i++) s4[tid + i * 256] = W4[tid + i * 256];
    }
    __syncthreads();
#pragma unroll
    for (int k4 = 0; k4 < 8; k4++) {
      float4 xv[4];
#pragma unroll
      for (int r = 0; r < 4; r++) xv[r] = xs4[(rs + 8 * r) * 32 + kt * 8 + k4];
#pragma unroll
      for (int j = 0; j < 4; j++) {
        float4 wv = ws4[(k4 * 4 + j) * 32 + cg];
#pragma unroll
        for (int r = 0; r < 4; r++) {
          float xsc = (j == 0) ? xv[r].x : (j == 1) ? xv[r].y : (j == 2) ? xv[r].z : xv[r].w;
          acc[r].x += xsc * wv.x;
          acc[r].y += xsc * wv.y;
          acc[r].z += xsc * wv.z;
          acc[r].w += xsc * wv.w;
        }
      }
    }
  }
  // stage scaled outputs to LDS (xs is dead), then repack fp16 with minimal live state
  __syncthreads();
  {
    float4* st = (float4*)xs;
#pragma unroll
    for (int r = 0; r < 4; r++) {
      const int row = row0 + rs + 8 * r;
      const float dn = dinv[row];
      float4 o = acc[r];
      o.x *= dn; o.y *= dn; o.z *= dn; o.w *= dn;
      st[(rs + 8 * r) * 32 + cg] = o;
    }
  }
  __syncthreads();
  {
    uint2* Yh2 = (uint2*)Yh;
#pragma unroll
    for (int i = 0; i < 4; i++) {
      const int idx = tid + i * 256;
      Yh2[(size_t)row0 * 32 + idx] = pack_half4(((const float4*)xs)[idx]);
    }
  }
}

// Final layer: A <- leaky(graphnorm(A)) in place + copy to out
__global__ __launch_bounds__(256) void apply_final_k(
    float* __restrict__ A, const int* __restrict__ batch,
    const float* __restrict__ meansum, const float* __restrict__ varsum,
    const float* __restrict__ cntinv,
    const float* __restrict__ gw, const float* __restrict__ gb, const float* __restrict__ gms,
    float* __restrict__ out2) {
  const int idx = blockIdx.x * 256 + threadIdx.x;   // over N*32 float4, exact grid
  const int n = idx >> 5;
  const int lane = idx & 31;
  const int g = batch[n];
  const float ci = cntinv[g];
  const float4 ms = ((const float4*)meansum)[g * 32 + lane];
  const float4 vs = ((const float4*)varsum)[g * 32 + lane];
  const float4 sv = ((const float4*)gms)[lane];
  const float4 wv = ((const float4*)gw)[lane];
  const float4 bv = ((const float4*)gb)[lane];
  float4 v = ((const float4*)A)[idx];
  float m, msc, var, rr;
  m = ms.x * ci; msc = m * sv.x; var = vs.x * ci - msc * (2.f * m - msc);
  rr = rsqrtf(var + EPS); v.x = (v.x - msc) * rr * wv.x + bv.x; v.x = (v.x > 0.f) ? v.x : SLOPE * v.x;
  m = ms.y * ci; msc = m * sv.y; var = vs.y * ci - msc * (2.f * m - msc);
  rr = rsqrtf(var + EPS); v.y = (v.y - msc) * rr * wv.y + bv.y; v.y = (v.y > 0.f) ? v.y : SLOPE * v.y;
  m = ms.z * ci; msc = m * sv.z; var = vs.z * ci - msc * (2.f * m - msc);
  rr = rsqrtf(var + EPS); v.z = (v.z - msc) * rr * wv.z + bv.z; v.z = (v.z > 0.f) ? v.z : SLOPE * v.z;
  m = ms.w * ci; msc = m * sv.w; var = vs.w * ci - msc * (2.f * m - msc);
  rr = rsqrtf(var + EPS); v.w = (v.w - msc) * rr * wv.w + bv.w; v.w = (v.w > 0.f) ? v.w : SLOPE * v.w;
  ((float4*)A)[idx] = v;
  ((float4*)out2)[idx] = v;
}

// ---------------- driver ----------------

extern "C" void kernel_launch(void* const* d_in, const int* in_sizes, int n_in,
                              void* d_out, int out_size, void* d_ws, size_t ws_size,
                              hipStream_t stream) {
  const float* x = (const float*)d_in[0];
  const int* ei = (const int*)d_in[1];
  const int* batch = (const int*)d_in[2];
  const float* W = (const float*)d_in[3];
  const float* b = (const float*)d_in[4];
  const float* gw = (const float*)d_in[5];
  const float* gb = (const float*)d_in[6];
  const float* gms = (const float*)d_in[7];
  float* out = (float*)d_out;

  const int* src = ei;
  const int* dst = ei + N_EDGES;

  // workspace layout (~31 MB total)
  __half* yh = (__half*)d_ws;                       // N*C halves (25.6 MB)
  int* cnt = (int*)(yh + (size_t)N_NODES * C);      // N
  int* row_ptr = cnt + N_NODES;                     // N+4
  int* cursor = row_ptr + N_NODES + 4;              // N
  int* src_s = cursor + N_NODES;                    // E
  float* dinv = (float*)(src_s + N_EDGES);          // N
  float* cntinv = dinv + N_NODES;                   // G
  float* stats = cntinv + G;                        // 6*G*C (3 layers x meansum+varsum)
  int* bsum = (int*)(stats + 6 * G * C);            // 256
  int* boff = bsum + 256;                           // 256

  hipMemsetAsync(cnt, 0, N_NODES * sizeof(int), stream);
  hipMemsetAsync(stats, 0, 6 * G * C * sizeof(float), stream);   // all 3 layers' stats, once
  hist_edges_k<<<(N_EDGES + 255) / 256, 256, 0, stream>>>(dst, cnt);
  graph_cnt_k<<<1, 64, 0, stream>>>(batch, cntinv);
  scan1_k<<<SCAN_BLOCKS, 256, 0, stream>>>(cnt, bsum);
  scan2_k<<<1, 256, 0, stream>>>(bsum, boff, row_ptr);
  scan3_k<<<SCAN_BLOCKS, 256, 0, stream>>>(cnt, boff, row_ptr, cursor);
  dinv_k<<<(N_NODES + 255) / 256, 256, 0, stream>>>(cnt, dinv);
  scatter_k<<<(N_EDGES + 255) / 256, 256, 0, stream>>>(src, dst, cursor, src_s);

  // layer 0 GEMM from the raw input -> fp16 Yh directly
  gemm_y_k<<<N_NODES / 32, 256, 0, stream>>>(x, W, dinv, yh);

  for (int l = 0; l < NL; l++) {
    float* slot = out + (size_t)N_NODES * C * (1 + l);
    float* meansum = stats + (size_t)l * 2 * G * C;
    float* varsum = meansum + G * C;
    agg_k<<<N_NODES / 8, 256, 0, stream>>>(yh, row_ptr, src_s, dinv, b + (size_t)l * C,
                                           batch, meansum, varsum, slot);
    if (l < NL - 1) {
      // fused: normalize+activate layer l (in place in history slot) and GEMM for layer l+1
      apply_gemm_k<<<N_NODES / 32, 256, 0, stream>>>(slot, batch, meansum, varsum, cntinv,
                                                     gw + (size_t)l * C, gb + (size_t)l * C,
                                                     gms + (size_t)l * C,
                                                     W + (size_t)(l + 1) * C * C, dinv, yh);
    } else {
      apply_final_k<<<(N_NODES * 32) / 256, 256, 0, stream>>>(slot, batch, meansum, varsum, cntinv,
                                                              gw + (size_t)l * C, gb + (size_t)l * C,
                                                              gms + (size_t)l * C, out);
    }
  }
}

// Round 9
// 787.970 us; speedup vs baseline: 1.0270x; 1.0270x over previous
//
#include <hip/hip_runtime.h>
#include <hip/hip_fp16.h>

#define N_NODES 100000
#define N_EDGES 1000000
#define C 128
#define NL 3
#define G 64
#define EPS 1e-5f
#define SLOPE 0.01f

#define SCAN_CH 392
#define SCAN_BLOCKS 256   // ceil(100000/392) == 256 exactly

// fp16 unpack: 4 channels per lane = 8 bytes (uint2)
static __device__ __forceinline__ float4 unpack_half4(uint2 u) {
  __half2 lo = *reinterpret_cast<__half2*>(&u.x);
  __half2 hi = *reinterpret_cast<__half2*>(&u.y);
  float2 a = __half22float2(lo);
  float2 b = __half22float2(hi);
  return make_float4(a.x, a.y, b.x, b.y);
}
static __device__ __forceinline__ uint2 pack_half4(float4 f) {
  __half2 lo = __floats2half2_rn(f.x, f.y);
  __half2 hi = __floats2half2_rn(f.z, f.w);
  uint2 u;
  u.x = *reinterpret_cast<unsigned int*>(&lo);
  u.y = *reinterpret_cast<unsigned int*>(&hi);
  return u;
}

// ---------------- preprocessing ----------------

__global__ __launch_bounds__(256) void hist_edges_k(const int* __restrict__ dst, int* __restrict__ cnt) {
  int i = blockIdx.x * 256 + threadIdx.x;
  if (i < N_EDGES) atomicAdd(&cnt[dst[i]], 1);
}

// multi-block scan, phase 1: per-chunk sums (coalesced)
__global__ __launch_bounds__(256) void scan1_k(const int* __restrict__ cnt, int* __restrict__ bsum) {
  __shared__ int red[256];
  const int b = blockIdx.x, t = threadIdx.x;
  const int s = b * SCAN_CH;
  const int e = min(s + SCAN_CH, N_NODES);
  int sum = 0;
  for (int i = s + t; i < e; i += 256) sum += cnt[i];
  red[t] = sum;
  __syncthreads();
  for (int off = 128; off > 0; off >>= 1) {
    if (t < off) red[t] += red[t + off];
    __syncthreads();
  }
  if (t == 0) bsum[b] = red[0];
}

// phase 2: exclusive scan of 256 block sums (one block)
// + fused per-graph counts (batch sorted -> binary search; threads 0..63, no barrier dep)
__global__ __launch_bounds__(256) void scan2_k(const int* __restrict__ bsum, int* __restrict__ boff,
                                               int* __restrict__ row_ptr,
                                               const int* __restrict__ batch, float* __restrict__ cntinv) {
  __shared__ int sh[256];
  const int t = threadIdx.x;
  sh[t] = bsum[t];
  __syncthreads();
  for (int off = 1; off < 256; off <<= 1) {
    int v = sh[t];
    int add = (t >= off) ? sh[t - off] : 0;
    __syncthreads();
    sh[t] = v + add;
    __syncthreads();
  }
  boff[t] = t ? sh[t - 1] : 0;
  if (t == 255) row_ptr[N_NODES] = sh[255];
  if (t < G) {
    auto lb = [&](int key) {
      int lo = 0, hi = N_NODES;
      while (lo < hi) { int mid = (lo + hi) >> 1; if (batch[mid] < key) lo = mid + 1; else hi = mid; }
      return lo;
    };
    const int a = lb(t), b = lb(t + 1);
    cntinv[t] = 1.0f / fmaxf((float)(b - a), 1.0f);
  }
}

// phase 3: per-chunk exclusive scan + global offset -> row_ptr, cursor; fused dinv
__global__ __launch_bounds__(256) void scan3_k(const int* __restrict__ cnt, const int* __restrict__ boff,
                                               int* __restrict__ row_ptr, int* __restrict__ cursor,
                                               float* __restrict__ dinv) {
  __shared__ int vals[SCAN_CH];
  __shared__ int tsum[256];
  const int b = blockIdx.x, t = threadIdx.x;
  const int s = b * SCAN_CH;
  const int e = min(s + SCAN_CH, N_NODES);
  const int len = e - s;
  for (int i = t; i < len; i += 256) {
    const int v = cnt[s + i];
    vals[i] = v;
    dinv[s + i] = rsqrtf((float)v + 1.0f);   // deg + self-loop (fused, was dinv_k)
  }
  __syncthreads();
  const int i0 = 2 * t, i1 = 2 * t + 1;
  const int a = (i0 < len) ? vals[i0] : 0;
  const int bb = (i1 < len) ? vals[i1] : 0;
  tsum[t] = a + bb;
  __syncthreads();
  for (int off = 1; off < 256; off <<= 1) {
    int v = tsum[t];
    int add = (t >= off) ? tsum[t - off] : 0;
    __syncthreads();
    tsum[t] = v + add;
    __syncthreads();
  }
  const int pre = (t ? tsum[t - 1] : 0) + boff[b];
  if (i0 < len) { row_ptr[s + i0] = pre; cursor[s + i0] = pre; }
  if (i1 < len) { row_ptr[s + i1] = pre + a; cursor[s + i1] = pre + a; }
}

__global__ __launch_bounds__(256) void scatter_k(const int* __restrict__ src, const int* __restrict__ dst,
                                                 int* __restrict__ cursor, int* __restrict__ src_s) {
  int i = blockIdx.x * 256 + threadIdx.x;
  if (i < N_EDGES) {
    int d = dst[i];
    int p = atomicAdd(&cursor[d], 1);
    src_s[p] = src[i];
  }
}

// ---------------- per-layer kernels ----------------

// Yh[n] = fp16( dinv[n] * (X[n] @ W) )   fp32 math, fp16 store via LDS repack
// (pack is quarantined in a post-sync region where the accumulator is dead -> no spill; verified R6/R7)
__global__ __launch_bounds__(256) void gemm_y_k(const float* __restrict__ X, const float* __restrict__ W,
                                                const float* __restrict__ dinv, __half* __restrict__ Yh) {
  __shared__ float xs[32 * C];   // 16 KB
  __shared__ float ws[32 * C];   // 16 KB (k-tile)
  const int tid = threadIdx.x;
  const int cg = tid & 31;    // cols cg*4 .. cg*4+3
  const int rs = tid >> 5;    // rows rs, rs+8, rs+16, rs+24
  const int row0 = blockIdx.x * 32;
  {
    const float4* X4 = (const float4*)(X + (size_t)row0 * C);
    float4* s4 = (float4*)xs;
#pragma unroll
    for (int i = 0; i < 4; i++) s4[tid + i * 256] = X4[tid + i * 256];
  }
  float4 acc[4];
#pragma unroll
  for (int r = 0; r < 4; r++) acc[r] = make_float4(0.f, 0.f, 0.f, 0.f);
  const float4* xs4 = (const float4*)xs;
  const float4* ws4 = (const float4*)ws;
#pragma unroll
  for (int kt = 0; kt < 4; kt++) {
    __syncthreads();
    {
      const float4* W4 = (const float4*)(W + (size_t)kt * 32 * C);
      float4* s4 = (float4*)ws;
#pragma unroll
      for (int i = 0; i < 4; i++) s4[tid + i * 256] = W4[tid + i * 256];
    }
    __syncthreads();
#pragma unroll
    for (int k4 = 0; k4 < 8; k4++) {
      float4 xv[4];
#pragma unroll
      for (int r = 0; r < 4; r++) xv[r] = xs4[(rs + 8 * r) * 32 + kt * 8 + k4];
#pragma unroll
      for (int j = 0; j < 4; j++) {
        float4 wv = ws4[(k4 * 4 + j) * 32 + cg];
#pragma unroll
        for (int r = 0; r < 4; r++) {
          float xsc = (j == 0) ? xv[r].x : (j == 1) ? xv[r].y : (j == 2) ? xv[r].z : xv[r].w;
          acc[r].x += xsc * wv.x;
          acc[r].y += xsc * wv.y;
          acc[r].z += xsc * wv.z;
          acc[r].w += xsc * wv.w;
        }
      }
    }
  }
  // stage scaled outputs to LDS (xs is dead), then repack fp16 with minimal live state
  __syncthreads();
  {
    float4* st = (float4*)xs;
#pragma unroll
    for (int r = 0; r < 4; r++) {
      const int row = row0 + rs + 8 * r;
      const float dn = dinv[row];
      float4 o = acc[r];
      o.x *= dn; o.y *= dn; o.z *= dn; o.w *= dn;
      st[(rs + 8 * r) * 32 + cg] = o;
    }
  }
  __syncthreads();
  {
    uint2* Yh2 = (uint2*)Yh;
#pragma unroll
    for (int i = 0; i < 4; i++) {
      const int idx = tid + i * 256;
      Yh2[(size_t)row0 * 32 + idx] = pack_half4(((const float4*)xs)[idx]);
    }
  }
}

// out[n] = dinv[n]*(Yh[n] + sum_{e in CSR[n]} Yh[src_e]) + b    (32 lanes per node)
// Pure gather+bias, NO block barrier (R8 showed barrier-coupled stats cost ~25us/dispatch:
// block retires at max-of-8 gather latencies instead of independent subgroup retirement).
__global__ __launch_bounds__(256) void agg_k(const __half* __restrict__ Yh, const int* __restrict__ row_ptr,
                                             const int* __restrict__ src_s, const float* __restrict__ dinv,
                                             const float* __restrict__ bias, float* __restrict__ out) {
  const int sub = threadIdx.x >> 5;
  const int lane = threadIdx.x & 31;
  const int n = blockIdx.x * 8 + sub;   // grid is exact: 12500*8 = 100000
  const uint2* Y2 = (const uint2*)Yh;   // 4 halves (8 B) per lane, 32 lanes per row
  float4 acc = unpack_half4(Y2[(size_t)n * 32 + lane]);
  const int e0 = row_ptr[n];
  const int e1 = row_ptr[n + 1];
  for (int e = e0; e < e1; e += 8) {
    const int c = e1 - e;   // >= 1
    int idx[8];
#pragma unroll
    for (int i = 0; i < 8; i++) idx[i] = src_s[(e + i < e1) ? e + i : e1 - 1];
    uint2 v[8];
#pragma unroll
    for (int i = 0; i < 8; i++) v[i] = Y2[(size_t)idx[i] * 32 + lane];
#pragma unroll
    for (int i = 0; i < 8; i++) {
      const float4 f = unpack_half4(v[i]);
      const float m = (i < c) ? 1.f : 0.f;
      acc.x += f.x * m;
      acc.y += f.y * m;
      acc.z += f.z * m;
      acc.w += f.w * m;
    }
  }
  const float dn = dinv[n];
  const float4 bb = ((const float4*)bias)[lane];
  float4 o;
  o.x = acc.x * dn + bb.x;
  o.y = acc.y * dn + bb.y;
  o.z = acc.z * dn + bb.z;
  o.w = acc.w * dn + bb.w;
  ((float4*)out)[(size_t)n * 32 + lane] = o;
}

__device__ __forceinline__ void flush4(float* dst, int g, int lane, float4 a) {
  float* p = dst + g * C + lane * 4;
  atomicAdd(p + 0, a.x);
  atomicAdd(p + 1, a.y);
  atomicAdd(p + 2, a.z);
  atomicAdd(p + 3, a.w);
}

// ONE pass over A: segment-sum of A and A*A over sorted batch -> meansum/varsum[G][C].
// Register-batched over 32-node runs -> only ~1.6M atomics total (measured fine R5/R7).
__global__ __launch_bounds__(256) void gn_sums_k(const float* __restrict__ A, const int* __restrict__ batch,
                                                 float* __restrict__ meansum, float* __restrict__ varsum) {
  const int sub = threadIdx.x >> 5;
  const int lane = threadIdx.x & 31;
  const int n0 = (blockIdx.x * 8 + sub) * 32;
  if (n0 >= N_NODES) return;
  const int nend = min(n0 + 32, N_NODES);
  const float4* A4 = (const float4*)A;
  float4 s = make_float4(0.f, 0.f, 0.f, 0.f);
  float4 q = make_float4(0.f, 0.f, 0.f, 0.f);
  int curg = batch[n0];
  for (int n = n0; n < nend; n++) {
    const int g = batch[n];
    if (g != curg) {
      flush4(meansum, curg, lane, s);
      flush4(varsum, curg, lane, q);
      s = make_float4(0.f, 0.f, 0.f, 0.f);
      q = make_float4(0.f, 0.f, 0.f, 0.f);
      curg = g;
    }
    const float4 v = A4[(size_t)n * 32 + lane];
    s.x += v.x; s.y += v.y; s.z += v.z; s.w += v.w;
    q.x += v.x * v.x; q.y += v.y * v.y; q.z += v.z * v.z; q.w += v.w * v.w;
  }
  flush4(meansum, curg, lane, s);
  flush4(varsum, curg, lane, q);
}

// Fused: A <- leaky(graphnorm(A)) in place (history slot), then Yh = fp16(dinv * (A @ W)) for next layer.
__global__ __launch_bounds__(256) void apply_gemm_k(
    float* __restrict__ A, const int* __restrict__ batch,
    const float* __restrict__ meansum, const float* __restrict__ varsum,
    const float* __restrict__ cntinv,
    const float* __restrict__ gw, const float* __restrict__ gb, const float* __restrict__ gms,
    const float* __restrict__ W, const float* __restrict__ dinv, __half* __restrict__ Yh) {
  __shared__ float xs[32 * C];   // 16 KB
  __shared__ float ws[32 * C];   // 16 KB
  const int tid = threadIdx.x;
  const int cg = tid & 31;
  const int rs = tid >> 5;
  const int row0 = blockIdx.x * 32;
  const float4 wv4 = ((const float4*)gw)[cg];
  const float4 bv4 = ((const float4*)gb)[cg];
  const float4 sv4 = ((const float4*)gms)[cg];
  float4* A4 = (float4*)A;
  const float4* MS4 = (const float4*)meansum;
  const float4* VS4 = (const float4*)varsum;
  float4* xs4w = (float4*)xs;
#pragma unroll
  for (int r = 0; r < 4; r++) {
    const int row = row0 + rs + 8 * r;
    const int g = batch[row];
    const float ci = cntinv[g];
    const float4 ms = MS4[g * 32 + cg];
    const float4 vs = VS4[g * 32 + cg];
    float4 v = A4[(size_t)row * 32 + cg];
    float m, msc, var, rr;
    m = ms.x * ci; msc = m * sv4.x; var = vs.x * ci - msc * (2.f * m - msc);
    rr = rsqrtf(var + EPS); v.x = (v.x - msc) * rr * wv4.x + bv4.x; v.x = (v.x > 0.f) ? v.x : SLOPE * v.x;
    m = ms.y * ci; msc = m * sv4.y; var = vs.y * ci - msc * (2.f * m - msc);
    rr = rsqrtf(var + EPS); v.y = (v.y - msc) * rr * wv4.y + bv4.y; v.y = (v.y > 0.f) ? v.y : SLOPE * v.y;
    m = ms.z * ci; msc = m * sv4.z; var = vs.z * ci - msc * (2.f * m - msc);
    rr = rsqrtf(var + EPS); v.z = (v.z - msc) * rr * wv4.z + bv4.z; v.z = (v.z > 0.f) ? v.z : SLOPE * v.z;
    m = ms.w * ci; msc = m * sv4.w; var = vs.w * ci - msc * (2.f * m - msc);
    rr = rsqrtf(var + EPS); v.w = (v.w - msc) * rr * wv4.w + bv4.w; v.w = (v.w > 0.f) ? v.w : SLOPE * v.w;
    A4[(size_t)row * 32 + cg] = v;            // history slot (activated layer output)
    xs4w[(rs + 8 * r) * 32 + cg] = v;         // stage for GEMM, same layout as gemm_y_k
  }
  float4 acc[4];
#pragma unroll
  for (int r = 0; r < 4; r++) acc[r] = make_float4(0.f, 0.f, 0.f, 0.f);
  const float4* xs4 = (const float4*)xs;
  const float4* ws4 = (const float4*)ws;
#pragma unroll
  for (int kt = 0; kt < 4; kt++) {
    __syncthreads();
    {
      const float4* W4 = (const float4*)(W + (size_t)kt * 32 * C);
      float4* s4 = (float4*)ws;
#pragma unroll
      for (int i = 0; i < 4; i++) s4[tid + i * 256] = W4[tid + i * 256];
    }
    __syncthreads();
#pragma unroll
    for (int k4 = 0; k4 < 8; k4++) {
      float4 xv[4];
#pragma unroll
      for (int r = 0; r < 4; r++) xv[r] = xs4[(rs + 8 * r) * 32 + kt * 8 + k4];
#pragma unroll
      for (int j = 0; j < 4; j++) {
        float4 wv = ws4[(k4 * 4 + j) * 32 + cg];
#pragma unroll
        for (int r = 0; r < 4; r++) {
          float xsc = (j == 0) ? xv[r].x : (j == 1) ? xv[r].y : (j == 2) ? xv[r].z : xv[r].w;
          acc[r].x += xsc * wv.x;
          acc[r].y += xsc * wv.y;
          acc[r].z += xsc * wv.z;
          acc[r].w += xsc * wv.w;
        }
      }
    }
  }
  // stage scaled outputs to LDS (xs is dead), then repack fp16 with minimal live state
  __syncthreads();
  {
    float4* st = (float4*)xs;
#pragma unroll
    for (int r = 0; r < 4; r++) {
      const int row = row0 + rs + 8 * r;
      const float dn = dinv[row];
      float4 o = acc[r];
      o.x *= dn; o.y *= dn; o.z *= dn; o.w *= dn;
      st[(rs + 8 * r) * 32 + cg] = o;
    }
  }
  __syncthreads();
  {
    uint2* Yh2 = (uint2*)Yh;
#pragma unroll
    for (int i = 0; i < 4; i++) {
      const int idx = tid + i * 256;
      Yh2[(size_t)row0 * 32 + idx] = pack_half4(((const float4*)xs)[idx]);
    }
  }
}

// Final layer: A <- leaky(graphnorm(A)) in place + copy to out
__global__ __launch_bounds__(256) void apply_final_k(
    float* __restrict__ A, const int* __restrict__ batch,
    const float* __restrict__ meansum, const float* __restrict__ varsum,
    const float* __restrict__ cntinv,
    const float* __restrict__ gw, const float* __restrict__ gb, const float* __restrict__ gms,
    float* __restrict__ out2) {
  const int idx = blockIdx.x * 256 + threadIdx.x;   // over N*32 float4, exact grid
  const int n = idx >> 5;
  const int lane = idx & 31;
  const int g = batch[n];
  const float ci = cntinv[g];
  const float4 ms = ((const float4*)meansum)[g * 32 + lane];
  const float4 vs = ((const float4*)varsum)[g * 32 + lane];
  const float4 sv = ((const float4*)gms)[lane];
  const float4 wv = ((const float4*)gw)[lane];
  const float4 bv = ((const float4*)gb)[lane];
  float4 v = ((const float4*)A)[idx];
  float m, msc, var, rr;
  m = ms.x * ci; msc = m * sv.x; var = vs.x * ci - msc * (2.f * m - msc);
  rr = rsqrtf(var + EPS); v.x = (v.x - msc) * rr * wv.x + bv.x; v.x = (v.x > 0.f) ? v.x : SLOPE * v.x;
  m = ms.y * ci; msc = m * sv.y; var = vs.y * ci - msc * (2.f * m - msc);
  rr = rsqrtf(var + EPS); v.y = (v.y - msc) * rr * wv.y + bv.y; v.y = (v.y > 0.f) ? v.y : SLOPE * v.y;
  m = ms.z * ci; msc = m * sv.z; var = vs.z * ci - msc * (2.f * m - msc);
  rr = rsqrtf(var + EPS); v.z = (v.z - msc) * rr * wv.z + bv.z; v.z = (v.z > 0.f) ? v.z : SLOPE * v.z;
  m = ms.w * ci; msc = m * sv.w; var = vs.w * ci - msc * (2.f * m - msc);
  rr = rsqrtf(var + EPS); v.w = (v.w - msc) * rr * wv.w + bv.w; v.w = (v.w > 0.f) ? v.w : SLOPE * v.w;
  ((float4*)A)[idx] = v;
  ((float4*)out2)[idx] = v;
}

// ---------------- driver ----------------

extern "C" void kernel_launch(void* const* d_in, const int* in_sizes, int n_in,
                              void* d_out, int out_size, void* d_ws, size_t ws_size,
                              hipStream_t stream) {
  const float* x = (const float*)d_in[0];
  const int* ei = (const int*)d_in[1];
  const int* batch = (const int*)d_in[2];
  const float* W = (const float*)d_in[3];
  const float* b = (const float*)d_in[4];
  const float* gw = (const float*)d_in[5];
  const float* gb = (const float*)d_in[6];
  const float* gms = (const float*)d_in[7];
  float* out = (float*)d_out;

  const int* src = ei;
  const int* dst = ei + N_EDGES;

  // workspace layout (~31 MB total)
  __half* yh = (__half*)d_ws;                       // N*C halves (25.6 MB)
  int* cnt = (int*)(yh + (size_t)N_NODES * C);      // N
  int* row_ptr = cnt + N_NODES;                     // N+4
  int* cursor = row_ptr + N_NODES + 4;              // N
  int* src_s = cursor + N_NODES;                    // E
  float* dinv = (float*)(src_s + N_EDGES);          // N
  float* cntinv = dinv + N_NODES;                   // G
  float* stats = cntinv + G;                        // 6*G*C (3 layers x meansum+varsum)
  int* bsum = (int*)(stats + 6 * G * C);            // 256
  int* boff = bsum + 256;                           // 256

  hipMemsetAsync(cnt, 0, N_NODES * sizeof(int), stream);
  hipMemsetAsync(stats, 0, 6 * G * C * sizeof(float), stream);   // all 3 layers' stats, once
  hist_edges_k<<<(N_EDGES + 255) / 256, 256, 0, stream>>>(dst, cnt);
  scan1_k<<<SCAN_BLOCKS, 256, 0, stream>>>(cnt, bsum);
  scan2_k<<<1, 256, 0, stream>>>(bsum, boff, row_ptr, batch, cntinv);
  scan3_k<<<SCAN_BLOCKS, 256, 0, stream>>>(cnt, boff, row_ptr, cursor, dinv);
  scatter_k<<<(N_EDGES + 255) / 256, 256, 0, stream>>>(src, dst, cursor, src_s);

  // layer 0 GEMM from the raw input -> fp16 Yh directly
  gemm_y_k<<<N_NODES / 32, 256, 0, stream>>>(x, W, dinv, yh);

  for (int l = 0; l < NL; l++) {
    float* slot = out + (size_t)N_NODES * C * (1 + l);
    float* meansum = stats + (size_t)l * 2 * G * C;
    float* varsum = meansum + G * C;
    agg_k<<<N_NODES / 8, 256, 0, stream>>>(yh, row_ptr, src_s, dinv, b + (size_t)l * C, slot);
    gn_sums_k<<<(N_NODES + 255) / 256, 256, 0, stream>>>(slot, batch, meansum, varsum);
    if (l < NL - 1) {
      // fused: normalize+activate layer l (in place in history slot) and GEMM for layer l+1
      apply_gemm_k<<<N_NODES / 32, 256, 0, stream>>>(slot, batch, meansum, varsum, cntinv,
                                                     gw + (size_t)l * C, gb + (size_t)l * C,
                                                     gms + (size_t)l * C,
                                                     W + (size_t)(l + 1) * C * C, dinv, yh);
    } else {
      apply_final_k<<<(N_NODES * 32) / 256, 256, 0, stream>>>(slot, batch, meansum, varsum, cntinv,
                                                              gw + (size_t)l * C, gb + (size_t)l * C,
                                                              gms + (size_t)l * C, out);
    }
  }
}